// Round 4
// baseline (654.679 us; speedup 1.0000x reference)
//
#include <hip/hip_runtime.h>
#include <hip/hip_bf16.h>

#define BB 16
#define CC 64
#define NN 2048
#define KK 4
#define NPART 4
#define JPER (NN / NPART)
#define TJ 128
#define ITEMS 64

typedef unsigned short u16;

__device__ __forceinline__ float bf2f(u16 u) {
    unsigned int x = ((unsigned int)u) << 16;
    float f;
    __builtin_memcpy(&f, &x, 4);
    return f;
}
__device__ __forceinline__ u16 f2bf(float f) {
    __hip_bfloat16 h = __float2bfloat16(f);
    u16 u;
    __builtin_memcpy(&u, &h, 2);
    return u;
}

// K1: transpose x (B,C,N) -> xt (B,N,C), compute xx = sum_c x^2
__global__ __launch_bounds__(256) void k_prep(const float* __restrict__ x,
                                              float* __restrict__ xt,
                                              float* __restrict__ xx) {
    int b = blockIdx.y;
    int n = blockIdx.x * 256 + threadIdx.x;
    const float* xb = x + (size_t)b * CC * NN;
    float v[CC];
    float s = 0.f;
#pragma unroll
    for (int c = 0; c < CC; c++) {
        v[c] = xb[(size_t)c * NN + n];
        s = fmaf(v[c], v[c], s);
    }
    float4* dst = (float4*)(xt + ((size_t)b * NN + n) * CC);
#pragma unroll
    for (int q = 0; q < 16; q++) {
        dst[q] = make_float4(v[4 * q], v[4 * q + 1], v[4 * q + 2], v[4 * q + 3]);
    }
    xx[b * NN + n] = s;
}

// K2: approx KNN, fp32, 4-way j-split, top-8 per (i, part)
__global__ __launch_bounds__(256) void k_knn_part(const float* __restrict__ xt,
                                                  const float* __restrict__ xx,
                                                  float* __restrict__ pv,
                                                  int* __restrict__ pi) {
    int part = blockIdx.x;
    int ich = blockIdx.y;
    int b = blockIdx.z;
    int tid = threadIdx.x;
    int i = ich * 256 + tid;

    __shared__ float tile[TJ][CC];
    __shared__ float xxs[TJ];

    float4 xi[16];
    const float4* xrow = (const float4*)(xt + ((size_t)b * NN + i) * CC);
#pragma unroll
    for (int q = 0; q < 16; q++) xi[q] = xrow[q];
    float xxi = xx[b * NN + i];

    float v[8];
    int id[8];
#pragma unroll
    for (int s = 0; s < 8; s++) {
        v[s] = -3.4e38f;
        id[s] = -1;
    }

    int j0 = part * JPER;
    for (int t = 0; t < JPER / TJ; t++) {
        int jb = j0 + t * TJ;
        __syncthreads();
        for (int g = tid; g < TJ * 16; g += 256) {
            int j = g >> 4, q = g & 15;
            ((float4*)&tile[j][0])[q] =
                ((const float4*)(xt + ((size_t)b * NN + jb + j) * CC))[q];
        }
        for (int g = tid; g < TJ; g += 256) xxs[g] = xx[b * NN + jb + g];
        __syncthreads();

        for (int j = 0; j < TJ; j++) {
            const float4* col = (const float4*)&tile[j][0];
            float s0 = 0.f, s1 = 0.f, s2 = 0.f, s3 = 0.f;
#pragma unroll
            for (int q = 0; q < 16; q += 4) {
                float4 c0 = col[q], c1 = col[q + 1], c2 = col[q + 2], c3 = col[q + 3];
                s0 = fmaf(c0.x, xi[q].x, fmaf(c0.y, xi[q].y, fmaf(c0.z, xi[q].z, fmaf(c0.w, xi[q].w, s0))));
                s1 = fmaf(c1.x, xi[q + 1].x, fmaf(c1.y, xi[q + 1].y, fmaf(c1.z, xi[q + 1].z, fmaf(c1.w, xi[q + 1].w, s1))));
                s2 = fmaf(c2.x, xi[q + 2].x, fmaf(c2.y, xi[q + 2].y, fmaf(c2.z, xi[q + 2].z, fmaf(c2.w, xi[q + 2].w, s2))));
                s3 = fmaf(c3.x, xi[q + 3].x, fmaf(c3.y, xi[q + 3].y, fmaf(c3.z, xi[q + 3].z, fmaf(c3.w, xi[q + 3].w, s3))));
            }
            float dot = (s0 + s1) + (s2 + s3);
            float nd = 2.f * dot - xxi - xxs[j];
            if (nd > v[7]) {
                float cv = nd;
                int ci = jb + j;
#pragma unroll
                for (int s = 0; s < 8; s++) {
                    bool gt = cv > v[s];
                    float nvv = gt ? cv : v[s];
                    int nii = gt ? ci : id[s];
                    float ov = gt ? v[s] : cv;
                    int oi = gt ? id[s] : ci;
                    v[s] = nvv;
                    id[s] = nii;
                    cv = ov;
                    ci = oi;
                }
            }
        }
    }
    size_t base = (((size_t)b * NN + i) * NPART + part) * 8;
#pragma unroll
    for (int s = 0; s < 8; s++) {
        pv[base + s] = v[s];
        pi[base + s] = id[s];
    }
}

// K3: fp64 refine of 32 candidates -> exact top-4 set
__global__ __launch_bounds__(256) void k_knn_merge(const float* __restrict__ xt,
                                                   const int* __restrict__ pi,
                                                   int* __restrict__ nidx) {
    int gid = blockIdx.x * 256 + threadIdx.x;
    int b = gid >> 11;
    int i = gid & (NN - 1);
    const float* xrow = xt + ((size_t)b * NN + i) * CC;
    float xi[CC];
#pragma unroll
    for (int c = 0; c < CC; c++) xi[c] = xrow[c];
    double xxi = 0.0;
#pragma unroll
    for (int c = 0; c < CC; c++) xxi += (double)xi[c] * (double)xi[c];

    double v4[4];
    int id4[4];
#pragma unroll
    for (int s = 0; s < 4; s++) {
        v4[s] = -1e300;
        id4[s] = 0x7fffffff;
    }

    size_t base = (size_t)gid * NPART * 8;
    for (int cnd = 0; cnd < NPART * 8; cnd++) {
        int j = pi[base + cnd];
        const float* xj = xt + ((size_t)b * NN + j) * CC;
        double dot = 0.0, sj = 0.0;
#pragma unroll
        for (int c = 0; c < CC; c++) {
            double a = (double)xi[c];
            double bb = (double)xj[c];
            dot += a * bb;
            sj += bb * bb;
        }
        double negd = 2.0 * dot - xxi - sj;
        double cv = negd;
        int ci = j;
#pragma unroll
        for (int s = 0; s < 4; s++) {
            bool take = (cv > v4[s]) || (cv == v4[s] && ci < id4[s]);
            double nv = take ? cv : v4[s];
            int ni = take ? ci : id4[s];
            double ov = take ? v4[s] : cv;
            int oi = take ? id4[s] : ci;
            v4[s] = nv;
            id4[s] = ni;
            cv = ov;
            ci = oi;
        }
    }
#pragma unroll
    for (int s = 0; s < 4; s++) nidx[(size_t)gid * 4 + s] = id4[s];
}

// K4: fused MLP. Block: 16 n x 4 k = 64 items, 256 threads (4 waves).
// lane = item; wave w handles an output-channel slice.
__global__ __launch_bounds__(256) void k_mlp(const float* __restrict__ xt,
                                             const int* __restrict__ nidx,
                                             const float* __restrict__ w1,
                                             const float* __restrict__ b1,
                                             const float* __restrict__ w2,
                                             const float* __restrict__ b2,
                                             const float* __restrict__ w3,
                                             const float* __restrict__ b3,
                                             float* __restrict__ out) {
    int nch = blockIdx.x;  // 0..127
    int b = blockIdx.y;
    int n0 = nch * 16;
    int tid = threadIdx.x;

    __shared__ u16 F[ITEMS][132];   // raw features, bf16: [item][128ch]
    __shared__ u16 E1[ITEMS][68];   // relu(e1), bf16: [item][64ch]
    __shared__ u16 E2[ITEMS][132];  // relu(e2), bf16: [item][128ch]
    __shared__ int ji[ITEMS];

    if (tid < ITEMS) ji[tid] = nidx[((size_t)b * NN + n0) * KK + tid];
    __syncthreads();

    // gather: F[item][0..63]=center, [64..127]=neighbor
    for (int g = tid; g < ITEMS * 32; g += 256) {
        int it = g >> 5, q = g & 31;
        int half = q >> 4, cq = q & 15;
        int srcn = half ? ji[it] : (n0 + (it >> 2));
        float4 vs = ((const float4*)(xt + ((size_t)b * NN + srcn) * CC))[cq];
        ushort4 u;
        u.x = f2bf(vs.x);
        u.y = f2bf(vs.y);
        u.z = f2bf(vs.z);
        u.w = f2bf(vs.w);
        *(ushort4*)&F[it][half * 64 + cq * 4] = u;
    }
    __syncthreads();

    int wv = __builtin_amdgcn_readfirstlane((int)(tid >> 6));
    int lane = tid & 63;  // item

    // e1: 64 outs, wave handles 16
    {
        float acc[16];
        int ob = wv * 16;
#pragma unroll
        for (int oi = 0; oi < 16; oi++) acc[oi] = b1[ob + oi];
        for (int c = 0; c < 128; c += 4) {
            ushort4 u = *(const ushort4*)&F[lane][c];
            float f0 = bf2f(u.x), f1 = bf2f(u.y), f2v = bf2f(u.z), f3 = bf2f(u.w);
#pragma unroll
            for (int oi = 0; oi < 16; oi++) {
                const float* wr = w1 + (size_t)(ob + oi) * 128 + c;
                acc[oi] = fmaf(wr[0], f0, fmaf(wr[1], f1, fmaf(wr[2], f2v, fmaf(wr[3], f3, acc[oi]))));
            }
        }
#pragma unroll
        for (int oi = 0; oi < 16; oi++) E1[lane][ob + oi] = f2bf(fmaxf(acc[oi], 0.f));
    }
    __syncthreads();

    // e2: 128 outs, wave handles 32. inputs: e[0..63]=E1, e[64..191]=relu(F)
    {
        float acc[32];
        int ob = wv * 32;
#pragma unroll
        for (int oi = 0; oi < 32; oi++) acc[oi] = b2[ob + oi];
        for (int c = 0; c < 64; c += 4) {
            ushort4 u = *(const ushort4*)&E1[lane][c];
            float e0 = bf2f(u.x), e1v = bf2f(u.y), e2v = bf2f(u.z), e3v = bf2f(u.w);
#pragma unroll
            for (int oi = 0; oi < 32; oi++) {
                const float* wr = w2 + (size_t)(ob + oi) * 192 + c;
                acc[oi] = fmaf(wr[0], e0, fmaf(wr[1], e1v, fmaf(wr[2], e2v, fmaf(wr[3], e3v, acc[oi]))));
            }
        }
        for (int c = 0; c < 128; c += 4) {
            ushort4 u = *(const ushort4*)&F[lane][c];
            float e0 = fmaxf(bf2f(u.x), 0.f), e1v = fmaxf(bf2f(u.y), 0.f);
            float e2v = fmaxf(bf2f(u.z), 0.f), e3v = fmaxf(bf2f(u.w), 0.f);
#pragma unroll
            for (int oi = 0; oi < 32; oi++) {
                const float* wr = w2 + (size_t)(ob + oi) * 192 + 64 + c;
                acc[oi] = fmaf(wr[0], e0, fmaf(wr[1], e1v, fmaf(wr[2], e2v, fmaf(wr[3], e3v, acc[oi]))));
            }
        }
#pragma unroll
        for (int oi = 0; oi < 32; oi++) E2[lane][ob + oi] = f2bf(fmaxf(acc[oi], 0.f));
    }
    __syncthreads();

    // e3: out ch o = wv*16+oi, r in {0,1}: inputs E2[r*64+c]. then max over k.
    {
        float a0[16], a1[16];
        int ob = wv * 16;
#pragma unroll
        for (int oi = 0; oi < 16; oi++) {
            a0[oi] = b3[ob + oi];
            a1[oi] = b3[ob + oi];
        }
        for (int c = 0; c < 64; c += 4) {
            ushort4 u0 = *(const ushort4*)&E2[lane][c];
            ushort4 u1 = *(const ushort4*)&E2[lane][64 + c];
            float p0 = bf2f(u0.x), p1 = bf2f(u0.y), p2 = bf2f(u0.z), p3 = bf2f(u0.w);
            float q0 = bf2f(u1.x), q1 = bf2f(u1.y), q2 = bf2f(u1.z), q3 = bf2f(u1.w);
#pragma unroll
            for (int oi = 0; oi < 16; oi++) {
                const float* wr = w3 + (size_t)(ob + oi) * 64 + c;
                a0[oi] = fmaf(wr[0], p0, fmaf(wr[1], p1, fmaf(wr[2], p2, fmaf(wr[3], p3, a0[oi]))));
                a1[oi] = fmaf(wr[0], q0, fmaf(wr[1], q1, fmaf(wr[2], q2, fmaf(wr[3], q3, a1[oi]))));
            }
        }
#pragma unroll
        for (int oi = 0; oi < 16; oi++) {
            float m0 = fmaxf(a0[oi], __shfl_xor(a0[oi], 1));
            m0 = fmaxf(m0, __shfl_xor(m0, 2));
            float m1 = fmaxf(a1[oi], __shfl_xor(a1[oi], 1));
            m1 = fmaxf(m1, __shfl_xor(m1, 2));
            if ((lane & 3) == 0) {
                int nl = lane >> 2;
                size_t obase = ((size_t)b * 64 + ob + oi) * 4096 + (size_t)(n0 + nl) * 2;
                out[obase] = m0;
                out[obase + 1] = m1;
            }
        }
    }
}

extern "C" void kernel_launch(void* const* d_in, const int* in_sizes, int n_in,
                              void* d_out, int out_size, void* d_ws, size_t ws_size,
                              hipStream_t stream) {
    const float* x = (const float*)d_in[0];
    const float* w1 = (const float*)d_in[1];
    const float* b1 = (const float*)d_in[2];
    const float* w2 = (const float*)d_in[3];
    const float* b2 = (const float*)d_in[4];
    const float* w3 = (const float*)d_in[5];
    const float* b3 = (const float*)d_in[6];
    float* out = (float*)d_out;

    // workspace layout
    float* xt = (float*)d_ws;                       // B*N*C fp32 = 8 MB
    float* xx = xt + (size_t)BB * NN * CC;          // B*N fp32
    float* pv = xx + (size_t)BB * NN;               // B*N*NPART*8 fp32
    int* pi = (int*)(pv + (size_t)BB * NN * NPART * 8);
    int* nidx = pi + (size_t)BB * NN * NPART * 8;   // B*N*K int

    k_prep<<<dim3(NN / 256, BB), 256, 0, stream>>>(x, xt, xx);
    k_knn_part<<<dim3(NPART, NN / 256, BB), 256, 0, stream>>>(xt, xx, pv, pi);
    k_knn_merge<<<dim3(BB * NN / 256), 256, 0, stream>>>(xt, pi, nidx);
    k_mlp<<<dim3(NN / 16, BB), 256, 0, stream>>>(xt, nidx, w1, b1, w2, b2, w3, b3, out);
}

// Round 5
// 189.057 us; speedup vs baseline: 3.4629x; 3.4629x over previous
//
#include <hip/hip_runtime.h>
#include <hip/hip_bf16.h>

#define BB 16
#define CC 64
#define NN 2048
#define KK 4
#define NCAND 24
#define TOPT 6

typedef unsigned short u16;
typedef __attribute__((ext_vector_type(4))) float f32x4;
typedef __attribute__((ext_vector_type(8))) short short8;

__device__ __forceinline__ float bf2f(u16 u) {
    unsigned int x = ((unsigned int)u) << 16;
    float f;
    __builtin_memcpy(&f, &x, 4);
    return f;
}
__device__ __forceinline__ u16 f2bf(float f) {
    __hip_bfloat16 h = __float2bfloat16(f);
    u16 u;
    __builtin_memcpy(&u, &h, 2);
    return u;
}
__device__ __forceinline__ unsigned int pk2(float a, float b) {
    return (unsigned int)f2bf(a) | ((unsigned int)f2bf(b) << 16);
}

// K1: transpose x (B,C,N) -> xt (B,N,C), compute xx = sum_c x^2
__global__ __launch_bounds__(256) void k_prep(const float* __restrict__ x,
                                              float* __restrict__ xt,
                                              float* __restrict__ xx) {
    int b = blockIdx.y;
    int n = blockIdx.x * 256 + threadIdx.x;
    const float* xb = x + (size_t)b * CC * NN;
    float v[CC];
    float s = 0.f;
#pragma unroll
    for (int c = 0; c < CC; c++) {
        v[c] = xb[(size_t)c * NN + n];
        s = fmaf(v[c], v[c], s);
    }
    float4* dst = (float4*)(xt + ((size_t)b * NN + n) * CC);
#pragma unroll
    for (int q = 0; q < 16; q++) {
        dst[q] = make_float4(v[4 * q], v[4 * q + 1], v[4 * q + 2], v[4 * q + 3]);
    }
    xx[b * NN + n] = s;
}

// K1b: pack weights to bf16 fragment-linear layout.
// dest index for (out,k): lane = ((k>>3)&3)*16 + (out&15), e = k&7,
// flat = ((cb*NKS + ks)*64 + lane)*8 + e  with cb = out>>4, ks = k>>5.
__global__ __launch_bounds__(256) void k_wprep(const float* __restrict__ w1,
                                               const float* __restrict__ w2,
                                               const float* __restrict__ w3,
                                               u16* __restrict__ wb1,
                                               u16* __restrict__ wb2,
                                               u16* __restrict__ wb3) {
    int t = blockIdx.x * 256 + threadIdx.x;
    int stride = gridDim.x * 256;
    for (int idx = t; idx < 64 * 128; idx += stride) {  // w1: 64 out x 128 k
        int o = idx >> 7, k = idx & 127;
        int cb = o >> 4, lr = o & 15, ks = k >> 5, g = (k >> 3) & 3, e = k & 7;
        wb1[((cb * 4 + ks) * 64 + g * 16 + lr) * 8 + e] = f2bf(w1[idx]);
    }
    for (int idx = t; idx < 128 * 192; idx += stride) {  // w2: 128 out x 192 k
        int o = idx / 192, k = idx - o * 192;
        int cb = o >> 4, lr = o & 15, ks = k >> 5, g = (k >> 3) & 3, e = k & 7;
        wb2[((cb * 6 + ks) * 64 + g * 16 + lr) * 8 + e] = f2bf(w2[idx]);
    }
    for (int idx = t; idx < 64 * 64; idx += stride) {  // w3: 64 out x 64 k
        int o = idx >> 6, k = idx & 63;
        int cb = o >> 4, lr = o & 15, ks = k >> 5, g = (k >> 3) & 3, e = k & 7;
        wb3[((cb * 2 + ks) * 64 + g * 16 + lr) * 8 + e] = f2bf(w3[idx]);
    }
}

// K2: MFMA Gram-tile KNN. Block: 64 i-rows, j in tiles of 128 over all 2048.
// score = 2*dot_bf16 - xx_j  (xx_i dropped: rank-invariant per row).
// 4 scan-threads/row keep top-6 of their 32-col slice -> 24 candidates/row.
__global__ __launch_bounds__(256) void k_knn2(const float* __restrict__ xt,
                                              const float* __restrict__ xx,
                                              int* __restrict__ cand) {
    int ib = blockIdx.x;  // 0..31
    int b = blockIdx.y;
    int tid = threadIdx.x;
    int i0 = ib * 64;

    __shared__ u16 Ab[64 * 64];    // swizzled, 8 KB
    __shared__ u16 Bb[128 * 64];   // swizzled, 16 KB
    __shared__ float S[64 * 132];  // padded scores, 33 KB
    __shared__ float xxs[128];

    // stage A-tile (block's own rows), fp32->bf16, XOR-swizzled
    {
        int row = tid >> 2, q = tid & 3;
        const float* sp = xt + ((size_t)b * NN + i0 + row) * CC + q * 16;
        float4 a0 = ((const float4*)sp)[0];
        float4 a1 = ((const float4*)sp)[1];
        float4 a2 = ((const float4*)sp)[2];
        float4 a3 = ((const float4*)sp)[3];
        uint4 u0, u1;
        u0.x = pk2(a0.x, a0.y); u0.y = pk2(a0.z, a0.w);
        u0.z = pk2(a1.x, a1.y); u0.w = pk2(a1.z, a1.w);
        u1.x = pk2(a2.x, a2.y); u1.y = pk2(a2.z, a2.w);
        u1.z = pk2(a3.x, a3.y); u1.w = pk2(a3.z, a3.w);
        int base = row * 128 + q * 32;
        int swz = (row & 7) << 4;
        *(uint4*)((char*)Ab + (base ^ swz)) = u0;
        *(uint4*)((char*)Ab + ((base + 16) ^ swz)) = u1;
    }
    __syncthreads();

    int w = tid >> 6, l = tid & 63;
    int lr = l & 15, lg = l >> 4;

    // A-fragments (rows w*16..w*16+15, K=64) hoisted to registers
    short8 af[2];
#pragma unroll
    for (int ks = 0; ks < 2; ks++) {
        int row = w * 16 + lr;
        int off = (row * 128 + ks * 64 + lg * 16) ^ ((row & 7) << 4);
        af[ks] = *(const short8*)((const char*)Ab + off);
    }

    float v[TOPT];
    int id[TOPT];
#pragma unroll
    for (int s = 0; s < TOPT; s++) {
        v[s] = -3.4e38f;
        id[s] = 0x7fffffff;
    }
    int srow = tid & 63, chunk = tid >> 6;

    for (int jt = 0; jt < NN / 128; jt++) {
        // stage B-tile (128 j-rows)
        {
            int row = tid >> 1, h = tid & 1;
            const float* sp = xt + ((size_t)b * NN + jt * 128 + row) * CC + h * 32;
            int base = row * 128 + h * 64;
            int swz = (row & 7) << 4;
#pragma unroll
            for (int j4 = 0; j4 < 4; j4++) {
                float4 a0 = ((const float4*)sp)[2 * j4];
                float4 a1 = ((const float4*)sp)[2 * j4 + 1];
                uint4 u;
                u.x = pk2(a0.x, a0.y); u.y = pk2(a0.z, a0.w);
                u.z = pk2(a1.x, a1.y); u.w = pk2(a1.z, a1.w);
                *(uint4*)((char*)Bb + ((base + j4 * 16) ^ swz)) = u;
            }
        }
        if (tid < 128) xxs[tid] = xx[b * NN + jt * 128 + tid];
        __syncthreads();

        // MFMA: wave w computes rows w*16..+15 x all 128 cols
        f32x4 acc[8];
#pragma unroll
        for (int cb = 0; cb < 8; cb++) acc[cb] = (f32x4){0.f, 0.f, 0.f, 0.f};
#pragma unroll
        for (int ks = 0; ks < 2; ks++) {
#pragma unroll
            for (int cb = 0; cb < 8; cb++) {
                int row = cb * 16 + lr;
                int off = (row * 128 + ks * 64 + lg * 16) ^ ((row & 7) << 4);
                short8 bf = *(const short8*)((const char*)Bb + off);
                acc[cb] = __builtin_amdgcn_mfma_f32_16x16x32_bf16(af[ks], bf, acc[cb], 0, 0, 0);
            }
        }
        // epilogue: score = 2*dot - xx_j -> S
#pragma unroll
        for (int cb = 0; cb < 8; cb++) {
            float xj = xxs[cb * 16 + lr];
#pragma unroll
            for (int q = 0; q < 4; q++) {
                int irow = w * 16 + lg * 4 + q;
                S[irow * 132 + cb * 16 + lr] = 2.f * acc[cb][q] - xj;
            }
        }
        __syncthreads();

        // scan: thread (srow, chunk) scans cols chunk*32..+31
        const float* sp = S + srow * 132 + chunk * 32;
        int jbase = jt * 128 + chunk * 32;
#pragma unroll
        for (int c = 0; c < 32; c += 4) {
            float4 sv = *(const float4*)(sp + c);
#pragma unroll
            for (int e = 0; e < 4; e++) {
                float s = (e == 0) ? sv.x : (e == 1) ? sv.y : (e == 2) ? sv.z : sv.w;
                if (s > v[TOPT - 1]) {
                    float cv = s;
                    int ci = jbase + c + e;
#pragma unroll
                    for (int t = 0; t < TOPT; t++) {
                        bool gt = cv > v[t];
                        float nv = gt ? cv : v[t];
                        int ni = gt ? ci : id[t];
                        float ov = gt ? v[t] : cv;
                        int oi = gt ? id[t] : ci;
                        v[t] = nv; id[t] = ni; cv = ov; ci = oi;
                    }
                }
            }
        }
        // next-iter stage writes Bb (disjoint from S); post-stage barrier orders everything
    }

    size_t base = ((size_t)b * NN + i0 + srow) * NCAND + chunk * TOPT;
#pragma unroll
    for (int s = 0; s < TOPT; s++) cand[base + s] = id[s];
}

// K3: fp64 refine of 24 candidates -> exact top-4 set
__global__ __launch_bounds__(256) void k_knn_merge(const float* __restrict__ xt,
                                                   const int* __restrict__ cand,
                                                   int* __restrict__ nidx) {
    int gid = blockIdx.x * 256 + threadIdx.x;
    int b = gid >> 11;
    int i = gid & (NN - 1);
    const float* xrow = xt + ((size_t)b * NN + i) * CC;
    float xi[CC];
#pragma unroll
    for (int c = 0; c < CC; c++) xi[c] = xrow[c];
    double xxi = 0.0;
#pragma unroll
    for (int c = 0; c < CC; c++) xxi += (double)xi[c] * (double)xi[c];

    double v4[4];
    int id4[4];
#pragma unroll
    for (int s = 0; s < 4; s++) {
        v4[s] = -1e300;
        id4[s] = 0x7fffffff;
    }

    size_t base = (size_t)gid * NCAND;
    for (int cnd = 0; cnd < NCAND; cnd++) {
        int j = cand[base + cnd];
        const float* xj = xt + ((size_t)b * NN + j) * CC;
        double dot = 0.0, sj = 0.0;
#pragma unroll
        for (int c = 0; c < CC; c++) {
            double a = (double)xi[c];
            double bb = (double)xj[c];
            dot += a * bb;
            sj += bb * bb;
        }
        double negd = 2.0 * dot - xxi - sj;
        double cv = negd;
        int ci = j;
#pragma unroll
        for (int s = 0; s < 4; s++) {
            bool take = (cv > v4[s]) || (cv == v4[s] && ci < id4[s]);
            double nv = take ? cv : v4[s];
            int ni = take ? ci : id4[s];
            double ov = take ? v4[s] : cv;
            int oi = take ? id4[s] : ci;
            v4[s] = nv;
            id4[s] = ni;
            cv = ov;
            ci = oi;
        }
    }
#pragma unroll
    for (int s = 0; s < 4; s++) nidx[(size_t)gid * 4 + s] = id4[s];
}

// K4: fused MFMA MLP. Block: 64 items (16 n x 4 k), 4 waves; wave w owns
// item-rows 16w..16w+15. Weights read as pre-packed bf16 fragments (L2-hot).
__global__ __launch_bounds__(256) void k_mlp(const float* __restrict__ xt,
                                             const int* __restrict__ nidx,
                                             const u16* __restrict__ wb1,
                                             const u16* __restrict__ wb2,
                                             const u16* __restrict__ wb3,
                                             const float* __restrict__ b1,
                                             const float* __restrict__ b2,
                                             const float* __restrict__ b3,
                                             float* __restrict__ out) {
    int nch = blockIdx.x;  // 0..127
    int b = blockIdx.y;
    int n0 = nch * 16;
    int tid = threadIdx.x;

    __shared__ u16 Fb[64 * 128];   // raw features bf16, swizzled (16 KB)
    __shared__ u16 E1b[64 * 64];   // relu(e1) (8 KB)
    __shared__ u16 E2b[64 * 128];  // relu(e2) (16 KB)
    __shared__ float Ob[64 * 36];  // e3 k-maxed, padded (9 KB)
    __shared__ int ji[64];

    if (tid < 64) ji[tid] = nidx[((size_t)b * NN + n0) * KK + tid];
    __syncthreads();

    // gather: F[item][0..63]=center, [64..127]=neighbor (swizzled bf16)
    for (int g = tid; g < 64 * 16; g += 256) {
        int it = g >> 4, q = g & 15;
        int half = q >> 3, cq = q & 7;
        int srcn = half ? ji[it] : (n0 + (it >> 2));
        const float* sp = xt + ((size_t)b * NN + srcn) * CC + cq * 8;
        float4 a0 = ((const float4*)sp)[0];
        float4 a1 = ((const float4*)sp)[1];
        uint4 u;
        u.x = pk2(a0.x, a0.y); u.y = pk2(a0.z, a0.w);
        u.z = pk2(a1.x, a1.y); u.w = pk2(a1.z, a1.w);
        int byte = (it * 256 + half * 128 + cq * 16) ^ ((it & 7) << 4);
        *(uint4*)((char*)Fb + byte) = u;
    }
    __syncthreads();

    int w = tid >> 6, l = tid & 63;
    int lr = l & 15, lg = l >> 4;
    int arow = w * 16 + lr;
    int aswz = (arow & 7) << 4;

    // ---- e1: [64 items x 128] x [128 x 64 out] ----
    {
        f32x4 acc[4];
#pragma unroll
        for (int cb = 0; cb < 4; cb++) acc[cb] = (f32x4){0.f, 0.f, 0.f, 0.f};
#pragma unroll
        for (int ks = 0; ks < 4; ks++) {
            int off = (arow * 256 + ks * 64 + lg * 16) ^ aswz;
            short8 a = *(const short8*)((const char*)Fb + off);
#pragma unroll
            for (int cb = 0; cb < 4; cb++) {
                short8 bw = *(const short8*)(wb1 + ((size_t)(cb * 4 + ks) * 64 + l) * 8);
                acc[cb] = __builtin_amdgcn_mfma_f32_16x16x32_bf16(a, bw, acc[cb], 0, 0, 0);
            }
        }
#pragma unroll
        for (int cb = 0; cb < 4; cb++) {
            float bias = b1[cb * 16 + lr];
#pragma unroll
            for (int q = 0; q < 4; q++) {
                int item = w * 16 + lg * 4 + q;
                float vv = fmaxf(acc[cb][q] + bias, 0.f);
                int byte = (item * 128 + (cb * 16 + lr) * 2) ^ ((item & 7) << 4);
                *(u16*)((char*)E1b + byte) = f2bf(vv);
            }
        }
    }
    __syncthreads();

    // ---- e2: [64 x 192] x [192 x 128 out]; k<64 from E1, k>=64 from relu(F) ----
    {
        f32x4 acc[8];
#pragma unroll
        for (int cb = 0; cb < 8; cb++) acc[cb] = (f32x4){0.f, 0.f, 0.f, 0.f};
#pragma unroll
        for (int ks = 0; ks < 6; ks++) {
            short8 a;
            if (ks < 2) {
                int off = (arow * 128 + ks * 64 + lg * 16) ^ aswz;
                a = *(const short8*)((const char*)E1b + off);
            } else {
                int off = (arow * 256 + (ks - 2) * 64 + lg * 16) ^ aswz;
                uint4 u = *(const uint4*)((const char*)Fb + off);
                unsigned int m;
                m = ((u.x >> 15) & 0x10001u) * 0xFFFFu; u.x &= ~m;
                m = ((u.y >> 15) & 0x10001u) * 0xFFFFu; u.y &= ~m;
                m = ((u.z >> 15) & 0x10001u) * 0xFFFFu; u.z &= ~m;
                m = ((u.w >> 15) & 0x10001u) * 0xFFFFu; u.w &= ~m;
                __builtin_memcpy(&a, &u, 16);
            }
#pragma unroll
            for (int cb = 0; cb < 8; cb++) {
                short8 bw = *(const short8*)(wb2 + ((size_t)(cb * 6 + ks) * 64 + l) * 8);
                acc[cb] = __builtin_amdgcn_mfma_f32_16x16x32_bf16(a, bw, acc[cb], 0, 0, 0);
            }
        }
#pragma unroll
        for (int cb = 0; cb < 8; cb++) {
            float bias = b2[cb * 16 + lr];
#pragma unroll
            for (int q = 0; q < 4; q++) {
                int item = w * 16 + lg * 4 + q;
                float vv = fmaxf(acc[cb][q] + bias, 0.f);
                int byte = (item * 256 + (cb * 16 + lr) * 2) ^ ((item & 7) << 4);
                *(u16*)((char*)E2b + byte) = f2bf(vv);
            }
        }
    }
    __syncthreads();

    // ---- e3: for r in {0,1}: [64 x 64] x [64 x 64 out]; k-max in-lane ----
#pragma unroll
    for (int r = 0; r < 2; r++) {
        f32x4 acc[4];
#pragma unroll
        for (int cb = 0; cb < 4; cb++) acc[cb] = (f32x4){0.f, 0.f, 0.f, 0.f};
#pragma unroll
        for (int ks = 0; ks < 2; ks++) {
            int off = (arow * 256 + r * 128 + ks * 64 + lg * 16) ^ aswz;
            short8 a = *(const short8*)((const char*)E2b + off);
#pragma unroll
            for (int cb = 0; cb < 4; cb++) {
                short8 bw = *(const short8*)(wb3 + ((size_t)(cb * 2 + ks) * 64 + l) * 8);
                acc[cb] = __builtin_amdgcn_mfma_f32_16x16x32_bf16(a, bw, acc[cb], 0, 0, 0);
            }
        }
        // regs q=0..3 are exactly the 4 k-neighbors of n_local = w*4 + lg
#pragma unroll
        for (int cb = 0; cb < 4; cb++) {
            float m = fmaxf(fmaxf(acc[cb][0], acc[cb][1]), fmaxf(acc[cb][2], acc[cb][3])) + b3[cb * 16 + lr];
            int o = cb * 16 + lr;
            int nl = w * 4 + lg;
            Ob[o * 36 + nl * 2 + r] = m;
        }
    }
    __syncthreads();

    // coalesced store: thread t -> out channel t>>2, 8 floats
    {
        int o = tid >> 2, q = tid & 3;
        float4 v0 = *(const float4*)&Ob[o * 36 + q * 8];
        float4 v1 = *(const float4*)&Ob[o * 36 + q * 8 + 4];
        float* dst = out + ((size_t)(b * 64 + o)) * 4096 + n0 * 2 + q * 8;
        ((float4*)dst)[0] = v0;
        ((float4*)dst)[1] = v1;
    }
}

extern "C" void kernel_launch(void* const* d_in, const int* in_sizes, int n_in,
                              void* d_out, int out_size, void* d_ws, size_t ws_size,
                              hipStream_t stream) {
    const float* x = (const float*)d_in[0];
    const float* w1 = (const float*)d_in[1];
    const float* b1 = (const float*)d_in[2];
    const float* w2 = (const float*)d_in[3];
    const float* b2 = (const float*)d_in[4];
    const float* w3 = (const float*)d_in[5];
    const float* b3 = (const float*)d_in[6];
    float* out = (float*)d_out;

    // workspace layout
    float* xt = (float*)d_ws;                         // B*N*C fp32 = 8 MB
    float* xx = xt + (size_t)BB * NN * CC;            // B*N
    int* nidx = (int*)(xx + (size_t)BB * NN);         // B*N*K
    int* cand = nidx + (size_t)BB * NN * KK;          // B*N*NCAND
    u16* wb1 = (u16*)(cand + (size_t)BB * NN * NCAND);
    u16* wb2 = wb1 + 64 * 128;
    u16* wb3 = wb2 + 128 * 192;

    k_prep<<<dim3(NN / 256, BB), 256, 0, stream>>>(x, xt, xx);
    k_wprep<<<dim3(32), 256, 0, stream>>>(w1, w2, w3, wb1, wb2, wb3);
    k_knn2<<<dim3(NN / 64, BB), 256, 0, stream>>>(xt, xx, cand);
    k_knn_merge<<<dim3(BB * NN / 256), 256, 0, stream>>>(xt, cand, nidx);
    k_mlp<<<dim3(NN / 16, BB), 256, 0, stream>>>(xt, nidx, wb1, wb2, wb3, b1, b2, b3, out);
}